// Round 1
// baseline (1838.668 us; speedup 1.0000x reference)
//
#include <hip/hip_runtime.h>
#include <stdint.h>

#define B_  2048
#define U_  64
#define D_  256
#define K_  1024
#define N_  (B_*U_)   // 131072 rows

typedef unsigned long long u64;

__device__ __forceinline__ float sqr_rn(float x) { return __fmul_rn(x, x); }

// e_sq[k] = sum_d E[k][d]^2, numpy pairwise order (256 = 128+128, 8-way unrolled blocks)
__global__ __launch_bounds__(64)
void esq_kernel(const float* __restrict__ E, float* __restrict__ esq) {
    int code = blockIdx.x * 64 + threadIdx.x;
    const float* row = E + (size_t)code * D_;
    float tot[2];
#pragma unroll
    for (int blk = 0; blk < 2; ++blk) {
        const float* p = row + blk * 128;
        float r[8];
#pragma unroll
        for (int j = 0; j < 8; ++j) r[j] = sqr_rn(p[j]);
        for (int i = 8; i < 128; i += 8) {
#pragma unroll
            for (int j = 0; j < 8; ++j) r[j] = __fadd_rn(r[j], sqr_rn(p[i + j]));
        }
        tot[blk] = __fadd_rn(__fadd_rn(__fadd_rn(r[0], r[1]), __fadd_rn(r[2], r[3])),
                             __fadd_rn(__fadd_rn(r[4], r[5]), __fadd_rn(r[6], r[7])));
    }
    esq[code] = __fadd_rn(tot[0], tot[1]);
}

// One block = 64 rows. Full z tile (64x256) in LDS (transposed + XOR swizzled),
// E staged in 64-code x 32-d chunks. 16x16 threads, 4x4 f32 accumulators.
// dist = (z_sq - 2*cross) + e_sq  (faithful f32 formula), argmin via packed u64 min.
__global__ __launch_bounds__(256)
void vq_kernel(const float* __restrict__ Z, const float* __restrict__ E,
               const float* __restrict__ esq, float* __restrict__ out) {
    extern __shared__ char smem[];
    float* zTs   = (float*)smem;            // 256*64 floats, d-major, swizzled (64KB)
    float* eTs   = zTs + 256 * 64;          // 32*64 floats (8KB)
    float* zsq_l = eTs + 32 * 64;           // 64
    float* esq_l = zsq_l + 64;              // 64
    unsigned* kst = (unsigned*)(esq_l + 64);// 64

    const int t  = threadIdx.x;
    const int tx = t & 15, ty = t >> 4;
    const int r0 = blockIdx.x * 64;

    const float4* Z4 = (const float4*)Z;
    const float4* E4 = (const float4*)E;

    // ---- stage full z tile: transposed (d-major) + swizzle (group ^ (d&15)) ----
#pragma unroll
    for (int i = 0; i < 16; ++i) {
        int f4  = t + 256 * i;          // 0..4095
        int row = f4 >> 6, d4 = f4 & 63;
        float4 v = Z4[(size_t)(r0 + row) * 64 + d4];
        int g = row >> 2, rr = row & 3;
        int d0 = d4 * 4;
        zTs[((d0 + 0) << 6) + ((g ^ ((d0 + 0) & 15)) << 2) + rr] = v.x;
        zTs[((d0 + 1) << 6) + ((g ^ ((d0 + 1) & 15)) << 2) + rr] = v.y;
        zTs[((d0 + 2) << 6) + ((g ^ ((d0 + 2) & 15)) << 2) + rr] = v.z;
        zTs[((d0 + 3) << 6) + ((g ^ ((d0 + 3) & 15)) << 2) + rr] = v.w;
    }
    __syncthreads();

    // ---- z_sq per row, numpy pairwise order ----
    if (t < 64) {
        int g = t >> 2, rr = t & 3;
        float tot[2];
#pragma unroll
        for (int blk = 0; blk < 2; ++blk) {
            int base = blk * 128;
            float r[8];
#pragma unroll
            for (int j = 0; j < 8; ++j) {
                int d = base + j;
                float x = zTs[(d << 6) + ((g ^ (d & 15)) << 2) + rr];
                r[j] = sqr_rn(x);
            }
            for (int i = 8; i < 128; i += 8) {
#pragma unroll
                for (int j = 0; j < 8; ++j) {
                    int d = base + i + j;
                    float x = zTs[(d << 6) + ((g ^ (d & 15)) << 2) + rr];
                    r[j] = __fadd_rn(r[j], sqr_rn(x));
                }
            }
            tot[blk] = __fadd_rn(__fadd_rn(__fadd_rn(r[0], r[1]), __fadd_rn(r[2], r[3])),
                                 __fadd_rn(__fadd_rn(r[4], r[5]), __fadd_rn(r[6], r[7])));
        }
        zsq_l[t] = __fadd_rn(tot[0], tot[1]);
    }
    __syncthreads();

    float acc[4][4];
    u64 runbest[4] = {~0ull, ~0ull, ~0ull, ~0ull};

    for (int kt = 0; kt < 16; ++kt) {
        const int c0 = kt * 64;
        if (t < 64) esq_l[t] = esq[c0 + t];
#pragma unroll
        for (int i2 = 0; i2 < 4; ++i2)
#pragma unroll
            for (int j = 0; j < 4; ++j) acc[i2][j] = 0.0f;

        for (int dc = 0; dc < 8; ++dc) {
            // stage 64-code x 32-d chunk of E (transposed + swizzled)
#pragma unroll
            for (int i = 0; i < 2; ++i) {
                int f4   = t + 256 * i;      // 0..511
                int code = f4 >> 3, d4l = f4 & 7;
                float4 v = E4[(size_t)(c0 + code) * 64 + dc * 8 + d4l];
                int g = code >> 2, cr = code & 3;
                int dl0 = d4l * 4;
                eTs[((dl0 + 0) << 6) + ((g ^ ((dl0 + 0) & 15)) << 2) + cr] = v.x;
                eTs[((dl0 + 1) << 6) + ((g ^ ((dl0 + 1) & 15)) << 2) + cr] = v.y;
                eTs[((dl0 + 2) << 6) + ((g ^ ((dl0 + 2) & 15)) << 2) + cr] = v.z;
                eTs[((dl0 + 3) << 6) + ((g ^ ((dl0 + 3) & 15)) << 2) + cr] = v.w;
            }
            __syncthreads();

            const float4* zT4 = (const float4*)zTs;
            const float4* eT4 = (const float4*)eTs;
#pragma unroll
            for (int dd = 0; dd < 32; ++dd) {
                int d = dc * 32 + dd;
                int m = dd & 15;                 // == d & 15
                float4 a = zT4[(d << 4) + (ty ^ m)];
                float4 b = eT4[(dd << 4) + (tx ^ m)];
                acc[0][0] = fmaf(a.x, b.x, acc[0][0]);
                acc[0][1] = fmaf(a.x, b.y, acc[0][1]);
                acc[0][2] = fmaf(a.x, b.z, acc[0][2]);
                acc[0][3] = fmaf(a.x, b.w, acc[0][3]);
                acc[1][0] = fmaf(a.y, b.x, acc[1][0]);
                acc[1][1] = fmaf(a.y, b.y, acc[1][1]);
                acc[1][2] = fmaf(a.y, b.z, acc[1][2]);
                acc[1][3] = fmaf(a.y, b.w, acc[1][3]);
                acc[2][0] = fmaf(a.z, b.x, acc[2][0]);
                acc[2][1] = fmaf(a.z, b.y, acc[2][1]);
                acc[2][2] = fmaf(a.z, b.z, acc[2][2]);
                acc[2][3] = fmaf(a.z, b.w, acc[2][3]);
                acc[3][0] = fmaf(a.w, b.x, acc[3][0]);
                acc[3][1] = fmaf(a.w, b.y, acc[3][1]);
                acc[3][2] = fmaf(a.w, b.z, acc[3][2]);
                acc[3][3] = fmaf(a.w, b.w, acc[3][3]);
            }
            __syncthreads();
        }

        // epilogue: dist + running per-thread best (packed bits<<32 | k, u64 min)
#pragma unroll
        for (int i2 = 0; i2 < 4; ++i2) {
            float zs = zsq_l[ty * 4 + i2];
#pragma unroll
            for (int j = 0; j < 4; ++j) {
                float c    = acc[i2][j];
                float dist = __fadd_rn(__fsub_rn(zs, __fmul_rn(2.0f, c)), esq_l[tx * 4 + j]);
                unsigned kidx = (unsigned)(c0 + tx * 4 + j);
                u64 key = ((u64)__float_as_uint(dist) << 32) | (u64)kidx;
                if (key < runbest[i2]) runbest[i2] = key;
            }
        }
        __syncthreads();  // protect esq_l/eTs before next k-tile overwrites
    }

    // reduce across the 16 tx lanes sharing each row group (deterministic)
#pragma unroll
    for (int i2 = 0; i2 < 4; ++i2) {
        u64 b = runbest[i2];
#pragma unroll
        for (int off = 8; off >= 1; off >>= 1) {
            u64 o = __shfl_xor(b, off, 64);
            if (o < b) b = o;
        }
        if (tx == 0) kst[ty * 4 + i2] = (unsigned)(b & 0xffffffffu);
    }
    __syncthreads();

    // gather: out[row] = E[k*]
    float4* O4 = (float4*)out;
#pragma unroll
    for (int i = 0; i < 16; ++i) {
        int f4  = t + 256 * i;
        int row = f4 >> 6, d4 = f4 & 63;
        unsigned k = kst[row];
        O4[(size_t)(r0 + row) * 64 + d4] = E4[(size_t)k * 64 + d4];
    }
}

extern "C" void kernel_launch(void* const* d_in, const int* in_sizes, int n_in,
                              void* d_out, int out_size, void* d_ws, size_t ws_size,
                              hipStream_t stream) {
    const float* Z = (const float*)d_in[0];
    const float* E = (const float*)d_in[1];
    float* out = (float*)d_out;
    float* esq = (float*)d_ws;   // 1024 floats of scratch

    esq_kernel<<<K_ / 64, 64, 0, stream>>>(E, esq);

    const int SMEM = (256 * 64 + 32 * 64 + 64 + 64 + 64) * 4;  // 74496 B
    hipFuncSetAttribute((const void*)vq_kernel,
                        hipFuncAttributeMaxDynamicSharedMemorySize, SMEM);
    vq_kernel<<<N_ / 64, 256, SMEM, stream>>>(Z, E, esq, out);
}